// Round 9
// baseline (946.873 us; speedup 1.0000x reference)
//
#include <hip/hip_runtime.h>
#include <hip/hip_bf16.h>
#include <math.h>

#define N_NODES 50000
#define N_EDGES 800000
#define FEAT 90
#define HD 128
#define STEPS 4
#define N_GRAPHS 100
#define SCAN_BLOCKS 196  // 196*256 = 50176 >= 50000
#define GRU_ROWS 128

typedef __attribute__((ext_vector_type(8))) short short8v;
typedef __attribute__((ext_vector_type(8))) unsigned int uint8v;
typedef __attribute__((ext_vector_type(4))) float f32x4;
typedef unsigned short ushort_t;
typedef unsigned int uint_t;

__device__ __forceinline__ float sigmoid_(float x) { return 1.f / (1.f + expf(-x)); }

__device__ __forceinline__ ushort_t f2bf(float x) {
    uint_t u = __float_as_uint(x);
    uint_t r = (u + 0x7fffu + ((u >> 16) & 1u)) >> 16;   // RNE
    return (ushort_t)r;
}
__device__ __forceinline__ float bf2f(ushort_t h) { return __uint_as_float(((uint_t)h) << 16); }
// packed element: (hi16 << 16) | lo16 ; value = f(hi) + f(lo)
__device__ __forceinline__ uint_t packf(float x) {
    ushort_t hi = f2bf(x);
    ushort_t lo = f2bf(x - bf2f(hi));
    return ((uint_t)hi << 16) | lo;
}
__device__ __forceinline__ float unpackf(uint_t u) {
    return __uint_as_float(u & 0xffff0000u) + __uint_as_float(u << 16);
}

__device__ __forceinline__ f32x4 mfma16(short8v a, short8v b, f32x4 c) {
    return __builtin_amdgcn_mfma_f32_16x16x32_bf16(a, b, c, 0, 0, 0);
}

// async global->LDS, 16B per lane; LDS dest = wave-uniform base + lane*16
__device__ __forceinline__ void gload_lds16(const void* g, void* l) {
    __builtin_amdgcn_global_load_lds(
        (const __attribute__((address_space(1))) unsigned int*)g,
        (__attribute__((address_space(3))) unsigned int*)l,
        16, 0, 0);
}

// ---------------- CSR build ----------------
__global__ void k_count(const int* __restrict__ dst, int* __restrict__ deg) {
    int e = blockIdx.x * 256 + threadIdx.x;
    if (e < N_EDGES) atomicAdd(&deg[dst[e]], 1);
}

// phase 1: per-block sums of deg (coalesced)
__global__ __launch_bounds__(256) void k_bsum(const int* __restrict__ deg,
                                              int* __restrict__ bsum) {
    int t = threadIdx.x, b = blockIdx.x;
    int v = b * 256 + t;
    int x = (v < N_NODES) ? deg[v] : 0;
#pragma unroll
    for (int off = 32; off > 0; off >>= 1) x += __shfl_down(x, off, 64);
    __shared__ int ws[4];
    if ((t & 63) == 0) ws[t >> 6] = x;
    __syncthreads();
    if (t == 0) bsum[b] = ws[0] + ws[1] + ws[2] + ws[3];
}

// phase 2: exclusive scan of the 196 block sums (single tiny block)
__global__ __launch_bounds__(256) void k_bscan(const int* __restrict__ bsum,
                                               int* __restrict__ bpre) {
    __shared__ int s[256];
    int t = threadIdx.x;
    int x = (t < SCAN_BLOCKS) ? bsum[t] : 0;
    s[t] = x;
    __syncthreads();
    for (int off = 1; off < 256; off <<= 1) {
        int y = (t >= off) ? s[t - off] : 0;
        __syncthreads();
        s[t] += y;
        __syncthreads();
    }
    if (t < SCAN_BLOCKS) bpre[t] = s[t] - x;
}

// phase 3: per-block 256-wide scan + block prefix, coalesced writes
__global__ __launch_bounds__(256) void k_wscan(const int* __restrict__ deg,
                                               const int* __restrict__ bpre,
                                               int* __restrict__ row_start,
                                               int* __restrict__ cursor) {
    __shared__ int s[256];
    int t = threadIdx.x, b = blockIdx.x;
    int v = b * 256 + t;
    int x = (v < N_NODES) ? deg[v] : 0;
    s[t] = x;
    __syncthreads();
    for (int off = 1; off < 256; off <<= 1) {
        int y = (t >= off) ? s[t - off] : 0;
        __syncthreads();
        s[t] += y;
        __syncthreads();
    }
    int excl = bpre[b] + s[t] - x;
    if (v < N_NODES) { row_start[v] = excl; cursor[v] = excl; }
    if (b == 0 && t == 0) row_start[N_NODES] = N_EDGES;  // all dst are valid nodes
}

__global__ void k_fill(const int* __restrict__ src, const int* __restrict__ dst,
                       int* __restrict__ cursor, int* __restrict__ esrc) {
    int e = blockIdx.x * 256 + threadIdx.x;
    if (e < N_EDGES) {
        int p = atomicAdd(&cursor[dst[e]], 1);
        esrc[p] = src[e];
    }
}

// ---------------- Wmi[i] = W_msg[i] @ W_ih  (f32, [4][128][384]) ----------------
__global__ __launch_bounds__(128) void k_wmi(const float* __restrict__ Wmsg,
                                             const float* __restrict__ Wih,
                                             float* __restrict__ Wmi) {
    int b = blockIdx.x;              // ((i*128)+r)*3 + cc
    int cc = b % 3;
    int ir = b / 3;
    int r = ir % 128, i = ir / 128;
    int c = cc * 128 + threadIdx.x;
    __shared__ float wrow[128];
    wrow[threadIdx.x] = Wmsg[((size_t)i * 128 + r) * 128 + threadIdx.x];
    __syncthreads();
    float acc = 0.f;
#pragma unroll 8
    for (int k = 0; k < 128; ++k) acc += wrow[k] * Wih[(size_t)k * 384 + c];
    Wmi[((size_t)i * 128 + r) * 384 + c] = acc;
}

// ---------------- pack B [128][384] f32 -> fragment-order split bf16 ----------------
// frag addressing: hi/lo[(((sl*24 + t)*64 + lane)*8 + j]
//   covers B[sl*32 + (lane>>4)*8 + j][t*16 + (lane&15)]
__global__ __launch_bounds__(256) void k_packB(const float* __restrict__ Wmi,
                                               const float* __restrict__ Whh,
                                               ushort_t* __restrict__ BmHi, ushort_t* __restrict__ BmLo,
                                               ushort_t* __restrict__ BhHi, ushort_t* __restrict__ BhLo) {
    int y = blockIdx.y;  // 0..3 -> Wmi step y ; 4 -> Whh
    const float* W;
    ushort_t *dhi, *dlo;
    if (y < 4) { W = Wmi + (size_t)y * 49152; dhi = BmHi + (size_t)y * 49152; dlo = BmLo + (size_t)y * 49152; }
    else       { W = Whh;                     dhi = BhHi;                     dlo = BhLo; }
    int g = blockIdx.x * 256 + threadIdx.x;   // 0..6143
    int lane = g & 63;
    int tt = (g >> 6) % 24;
    int sl = (g >> 6) / 24;
    int kb = sl * 32 + (lane >> 4) * 8;
    int c = tt * 16 + (lane & 15);
    short8v h8, l8;
#pragma unroll
    for (int j = 0; j < 8; ++j) {
        float w = W[(size_t)(kb + j) * 384 + c];
        ushort_t hi = f2bf(w);
        ushort_t lo = f2bf(w - bf2f(hi));
        h8[j] = (short)hi;
        l8[j] = (short)lo;
    }
    size_t o = (((size_t)sl * 24 + tt) * 64 + lane) * 8;
    *(short8v*)&dhi[o] = h8;
    *(short8v*)&dlo[o] = l8;
}

// ---------------- Embedding: h = relu(x @ Wemb) -> packed split bf16 ----------------
__global__ __launch_bounds__(256) void k_embed(const float* __restrict__ x,
                                               const float* __restrict__ Wemb,
                                               uint_t* __restrict__ hp) {
    __shared__ __align__(16) float a_s[32 * 96];
    __shared__ __align__(16) float w_s[96 * 128];
    int t = threadIdx.x;
    int n0 = blockIdx.x * 32;
    for (int i = t; i < 96 * 128; i += 256) {
        int k = i >> 7;
        w_s[i] = (k < FEAT) ? Wemb[i] : 0.f;
    }
    for (int i = t; i < 32 * 96; i += 256) {
        int r = i / 96, k = i - r * 96;
        int n = n0 + r;
        a_s[i] = (k < FEAT && n < N_NODES) ? x[(size_t)n * FEAT + k] : 0.f;
    }
    __syncthreads();
    int tx = t & 63, rg = t >> 6;
    float acc[8][2];
#pragma unroll
    for (int r = 0; r < 8; ++r) { acc[r][0] = 0.f; acc[r][1] = 0.f; }
    for (int k0 = 0; k0 < 96; k0 += 4) {
        float a4[8][4];
#pragma unroll
        for (int r = 0; r < 8; ++r)
            *(float4*)a4[r] = *(const float4*)&a_s[(rg * 8 + r) * 96 + k0];
#pragma unroll
        for (int j = 0; j < 4; ++j) {
            float w0 = w_s[(k0 + j) * 128 + tx];
            float w1 = w_s[(k0 + j) * 128 + tx + 64];
#pragma unroll
            for (int r = 0; r < 8; ++r) {
                acc[r][0] += a4[r][j] * w0;
                acc[r][1] += a4[r][j] * w1;
            }
        }
    }
#pragma unroll
    for (int r = 0; r < 8; ++r) {
        int n = n0 + rg * 8 + r;
        if (n < N_NODES) {
            size_t o = (size_t)n * HD + tx;
            hp[o]      = packf(fmaxf(acc[r][0], 0.f));
            hp[o + 64] = packf(fmaxf(acc[r][1], 0.f));
        }
    }
}

// ---------------- gather: agg[v] = sum_{e in CSR[v]} h[src_e]  (packed in/out) ----------------
__global__ __launch_bounds__(256) void k_gather(const uint_t* __restrict__ hp,
                                                const int* __restrict__ row_start,
                                                const int* __restrict__ esrc,
                                                uint_t* __restrict__ aggp) {
    int lane = threadIdx.x & 63;
    int wid = threadIdx.x >> 6;
    int v = blockIdx.x * 4 + wid;           // 50000 = 12500*4 exact
    int beg = row_start[v], end = row_start[v + 1];
    int off = lane * 2;
    float a0 = 0.f, a1 = 0.f;
    int j = beg;
    for (; j + 4 <= end; j += 4) {
        int s0 = esrc[j], s1 = esrc[j + 1], s2 = esrc[j + 2], s3 = esrc[j + 3];
        uint2 u0 = *(const uint2*)&hp[(size_t)s0 * HD + off];
        uint2 u1 = *(const uint2*)&hp[(size_t)s1 * HD + off];
        uint2 u2 = *(const uint2*)&hp[(size_t)s2 * HD + off];
        uint2 u3 = *(const uint2*)&hp[(size_t)s3 * HD + off];
        a0 += unpackf(u0.x) + unpackf(u1.x) + unpackf(u2.x) + unpackf(u3.x);
        a1 += unpackf(u0.y) + unpackf(u1.y) + unpackf(u2.y) + unpackf(u3.y);
    }
    for (; j + 2 <= end; j += 2) {
        int s0 = esrc[j], s1 = esrc[j + 1];
        uint2 u0 = *(const uint2*)&hp[(size_t)s0 * HD + off];
        uint2 u1 = *(const uint2*)&hp[(size_t)s1 * HD + off];
        a0 += unpackf(u0.x) + unpackf(u1.x);
        a1 += unpackf(u0.y) + unpackf(u1.y);
    }
    if (j < end) {
        uint2 u0 = *(const uint2*)&hp[(size_t)esrc[j] * HD + off];
        a0 += unpackf(u0.x);
        a1 += unpackf(u0.y);
    }
    *(uint2*)&aggp[(size_t)v * HD + off] = make_uint2(packf(a0), packf(a1));
}

// ---------------- fused GRU via MFMA, async global_load_lds double-buffered staging ----------------
// gates[N,384] = [agg | h] @ [Wmi ; Whh], split-bf16 3-term MFMA, in-register epilogue.
// block: 512 thr = 8 waves (wr row-group, wc col-half), tile 128 rows.
// 16 phases = (k-group 0..7) x (hi/lo half); 24KB per phase, 2x24KB ping-pong via global_load_lds.
__global__ __launch_bounds__(512, 4) void k_gru_mfma(const uint_t* __restrict__ aggp,
                                                     uint_t* __restrict__ hp,
                                                     const ushort_t* __restrict__ BmHi,
                                                     const ushort_t* __restrict__ BmLo,
                                                     const ushort_t* __restrict__ BhHi,
                                                     const ushort_t* __restrict__ BhLo,
                                                     const float* __restrict__ bih,
                                                     const float* __restrict__ bhh) {
    __shared__ __align__(16) ushort_t bsm[2][12288];  // 2 x 24KB half-slice buffers
    int t = threadIdx.x;          // 0..511
    int lane = t & 63;
    int wid = t >> 6;             // 0..7
    int wr = wid >> 1, wc = wid & 1;
    int row_base = blockIdx.x * GRU_ROWS + wr * 32;
    int ar0 = min(row_base + (lane & 15), N_NODES - 1);
    int ar1 = min(row_base + 16 + (lane & 15), N_NODES - 1);
    int kcol = (lane >> 4) * 8;

    f32x4 accR[2][4], accZ[2][4], accXN[2][4], accHN[2][4];
#pragma unroll
    for (int rf = 0; rf < 2; ++rf)
#pragma unroll
        for (int q = 0; q < 4; ++q) {
            accR[rf][q] = (f32x4)0.f; accZ[rf][q] = (f32x4)0.f;
            accXN[rf][q] = (f32x4)0.f; accHN[rf][q] = (f32x4)0.f;
        }

    // stage phase pp's 24KB half-slice into bsm[pp&1] via async global_load_lds.
    // wave w copies 3 x 1KB chunks: lds base wave-uniform, global addr per-lane.
    auto stage = [&](int pp) {
        const int k2 = pp >> 1, half2 = pp & 1;
        const ushort_t* base = (k2 >> 2) ? (half2 ? BhLo : BhHi) : (half2 ? BmLo : BmHi);
        const uint4* g = (const uint4*)(base + (size_t)(k2 & 3) * 12288);
        uint4* d = (uint4*)bsm[pp & 1];
        const int cb = wid << 6;   // wave chunk base, uint4 units
#pragma unroll
        for (int i = 0; i < 3; ++i)
            gload_lds16(&g[cb + i * 512 + lane], &d[cb + i * 512]);
    };

    // prologue: A for group 0 + stage phase 0
    uint8v u0 = *(const uint8v*)&aggp[(size_t)ar0 * HD + kcol];
    uint8v u1 = *(const uint8v*)&aggp[(size_t)ar1 * HD + kcol];
    stage(0);
    __syncthreads();

#pragma unroll
    for (int k = 0; k < 8; ++k) {
        const int src = k >> 2;       // 0: agg/Wmi, 1: h/Whh
        // extract A fragments once per group (live across hi+lo)
        short8v a0h, a0l, a1h, a1l;
#pragma unroll
        for (int j = 0; j < 8; ++j) {
            a0h[j] = (short)(u0[j] >> 16); a0l[j] = (short)(u0[j] & 0xffffu);
            a1h[j] = (short)(u1[j] >> 16); a1l[j] = (short)(u1[j] & 0xffffu);
        }
        // ---- hi phase (reads bsm[0]): 2 terms Ah*Bh + Al*Bh ----
        stage(2 * k + 1);
        {
            const ushort_t* bb = bsm[0];
#pragma unroll
            for (int grp = 0; grp < 3; ++grp) {
                auto& gate = (grp == 0) ? accR : (grp == 1) ? accZ : (src == 0) ? accXN : accHN;
#pragma unroll
                for (int q = 0; q < 4; ++q) {
                    int tt = grp * 8 + wc * 4 + q;
                    short8v b = *(const short8v*)&bb[(tt * 64 + lane) * 8];
                    gate[0][q] = mfma16(a0h, b, gate[0][q]);
                    gate[0][q] = mfma16(a0l, b, gate[0][q]);
                    gate[1][q] = mfma16(a1h, b, gate[1][q]);
                    gate[1][q] = mfma16(a1l, b, gate[1][q]);
                }
            }
        }
        __syncthreads();
        // ---- lo phase (reads bsm[1]): 1 term Ah*Bl ----
        if (k < 7) {
            const uint_t* Ap2 = ((k + 1) >> 2) ? hp : aggp;
            const int kb2 = ((k + 1) & 3) * 32 + kcol;
            u0 = *(const uint8v*)&Ap2[(size_t)ar0 * HD + kb2];
            u1 = *(const uint8v*)&Ap2[(size_t)ar1 * HD + kb2];
            stage(2 * k + 2);
        }
        {
            const ushort_t* bb = bsm[1];
#pragma unroll
            for (int grp = 0; grp < 3; ++grp) {
                auto& gate = (grp == 0) ? accR : (grp == 1) ? accZ : (src == 0) ? accXN : accHN;
#pragma unroll
                for (int q = 0; q < 4; ++q) {
                    int tt = grp * 8 + wc * 4 + q;
                    short8v b = *(const short8v*)&bb[(tt * 64 + lane) * 8];
                    gate[0][q] = mfma16(a0h, b, gate[0][q]);
                    gate[1][q] = mfma16(a1h, b, gate[1][q]);
                }
            }
        }
        __syncthreads();
    }

#pragma unroll
    for (int rf = 0; rf < 2; ++rf) {
#pragma unroll
        for (int q = 0; q < 4; ++q) {
            int c = wc * 64 + q * 16 + (lane & 15);
            float bir = bih[c],       bhr = bhh[c];
            float biz = bih[c + 128], bhz = bhh[c + 128];
            float bin_ = bih[c + 256], bhn = bhh[c + 256];
#pragma unroll
            for (int j = 0; j < 4; ++j) {
                int row = row_base + rf * 16 + ((lane >> 4) << 2) + j;
                if (row < N_NODES) {
                    float rr = sigmoid_(accR[rf][q][j] + bir + bhr);
                    float zz = sigmoid_(accZ[rf][q][j] + biz + bhz);
                    float nn = tanhf(accXN[rf][q][j] + bin_ + rr * (accHN[rf][q][j] + bhn));
                    size_t idx = (size_t)row * HD + c;
                    float hold = unpackf(hp[idx]);
                    hp[idx] = packf((1.f - zz) * nn + zz * hold);
                }
            }
        }
    }
}

// ---------------- pooling ----------------
#define POOL_CHUNK 256
__global__ __launch_bounds__(128) void k_pool(const uint_t* __restrict__ hp,
                                              const int* __restrict__ batch,
                                              float* __restrict__ pooled) {
    int t = threadIdx.x;  // 128 cols
    int n0 = blockIdx.x * POOL_CHUNK;
    int nend = n0 + POOL_CHUNK;
    if (nend > N_NODES) nend = N_NODES;
    float acc = 0.f;
    int cur = batch[n0];
    for (int n = n0; n < nend; ++n) {
        int g = batch[n];
        if (g != cur) {
            atomicAdd(&pooled[(size_t)cur * HD + t], acc);
            acc = 0.f;
            cur = g;
        }
        acc += fmaxf(unpackf(hp[(size_t)n * HD + t]), 0.f);  // fused final relu
    }
    atomicAdd(&pooled[(size_t)cur * HD + t], acc);
}

// ---------------- output MLP (counts via binary search on sorted batch) ----------------
__global__ __launch_bounds__(128) void k_out(const float* __restrict__ pooled,
                                             const int* __restrict__ batch,
                                             const float* __restrict__ W1,
                                             const float* __restrict__ b1,
                                             const float* __restrict__ W2,
                                             const float* __restrict__ b2,
                                             float* __restrict__ out) {
    __shared__ float row[128];
    __shared__ float red[128];
    int t = threadIdx.x;
    int g = blockIdx.x;
    int lo0 = 0, hi0 = N_NODES;
    while (lo0 < hi0) { int mid = (lo0 + hi0) >> 1; if (batch[mid] < g) lo0 = mid + 1; else hi0 = mid; }
    int lo1 = lo0, hi1 = N_NODES;
    while (lo1 < hi1) { int mid = (lo1 + hi1) >> 1; if (batch[mid] < g + 1) lo1 = mid + 1; else hi1 = mid; }
    float cnt = (float)(lo1 - lo0);
    if (cnt < 1.f) cnt = 1.f;
    row[t] = pooled[(size_t)g * HD + t] / cnt;
    __syncthreads();
    float acc = b1[t];
#pragma unroll 4
    for (int k = 0; k < HD; ++k) acc += row[k] * W1[k * HD + t];
    float hv = fmaxf(acc, 0.f);
    red[t] = hv * W2[t];
    __syncthreads();
    for (int off = 64; off > 0; off >>= 1) {
        if (t < off) red[t] += red[t + off];
        __syncthreads();
    }
    if (t == 0) {
        float xv = red[0] + b2[0];
        out[g] = fmaxf(xv, 0.f) + log1pf(expf(-fabsf(xv)));
    }
}

extern "C" void kernel_launch(void* const* d_in, const int* in_sizes, int n_in,
                              void* d_out, int out_size, void* d_ws, size_t ws_size,
                              hipStream_t stream) {
    (void)in_sizes; (void)n_in; (void)out_size; (void)ws_size;
    const float* x    = (const float*)d_in[0];
    const int*   ei   = (const int*)d_in[1];
    const int*   batch= (const int*)d_in[2];
    const float* Wemb = (const float*)d_in[3];
    const float* Wmsg = (const float*)d_in[4];
    const float* Wih  = (const float*)d_in[5];
    const float* Whh  = (const float*)d_in[6];
    const float* bih  = (const float*)d_in[7];
    const float* bhh  = (const float*)d_in[8];
    const float* W1   = (const float*)d_in[9];
    const float* b1   = (const float*)d_in[10];
    const float* W2   = (const float*)d_in[11];
    const float* b2   = (const float*)d_in[12];
    float* out = (float*)d_out;

    const int* e_src = ei;
    const int* e_dst = ei + N_EDGES;

    char* ws = (char*)d_ws;
    size_t off = 0;
    auto alloc = [&](size_t bytes) -> void* {
        void* p = ws + off;
        off = (off + bytes + 255) & ~(size_t)255;
        return p;
    };
    uint_t* hp       = (uint_t*)alloc((size_t)N_NODES * HD * 4);
    uint_t* aggp     = (uint_t*)alloc((size_t)N_NODES * HD * 4);
    float* Wmi       = (float*)alloc((size_t)STEPS * 128 * 384 * 4);
    ushort_t* BmHi   = (ushort_t*)alloc((size_t)STEPS * 128 * 384 * 2);
    ushort_t* BmLo   = (ushort_t*)alloc((size_t)STEPS * 128 * 384 * 2);
    ushort_t* BhHi   = (ushort_t*)alloc((size_t)128 * 384 * 2);
    ushort_t* BhLo   = (ushort_t*)alloc((size_t)128 * 384 * 2);
    float* pooled    = (float*)alloc((size_t)N_GRAPHS * HD * 4);
    int* deg         = (int*)alloc((size_t)N_NODES * 4);
    int* row_start   = (int*)alloc((size_t)(N_NODES + 1) * 4);
    int* cursor      = (int*)alloc((size_t)N_NODES * 4);
    int* esrc        = (int*)alloc((size_t)N_EDGES * 4);
    int* bsum        = (int*)alloc((size_t)SCAN_BLOCKS * 4);
    int* bpre        = (int*)alloc((size_t)SCAN_BLOCKS * 4);

    hipMemsetAsync(deg, 0, (size_t)N_NODES * 4, stream);
    hipMemsetAsync(pooled, 0, (size_t)N_GRAPHS * HD * 4, stream);

    k_count<<<(N_EDGES + 255) / 256, 256, 0, stream>>>(e_dst, deg);
    k_bsum<<<SCAN_BLOCKS, 256, 0, stream>>>(deg, bsum);
    k_bscan<<<1, 256, 0, stream>>>(bsum, bpre);
    k_wscan<<<SCAN_BLOCKS, 256, 0, stream>>>(deg, bpre, row_start, cursor);
    k_fill<<<(N_EDGES + 255) / 256, 256, 0, stream>>>(e_src, e_dst, cursor, esrc);

    k_wmi<<<STEPS * 128 * 3, 128, 0, stream>>>(Wmsg, Wih, Wmi);
    k_packB<<<dim3(24, 5), 256, 0, stream>>>(Wmi, Whh, BmHi, BmLo, BhHi, BhLo);

    k_embed<<<(N_NODES + 31) / 32, 256, 0, stream>>>(x, Wemb, hp);

    for (int i = 0; i < STEPS; ++i) {
        k_gather<<<N_NODES / 4, 256, 0, stream>>>(hp, row_start, esrc, aggp);
        k_gru_mfma<<<(N_NODES + GRU_ROWS - 1) / GRU_ROWS, 512, 0, stream>>>(
            aggp, hp,
            BmHi + (size_t)i * 49152, BmLo + (size_t)i * 49152,
            BhHi, BhLo, bih, bhh);
    }

    k_pool<<<(N_NODES + POOL_CHUNK - 1) / POOL_CHUNK, 128, 0, stream>>>(hp, batch, pooled);
    k_out<<<N_GRAPHS, 128, 0, stream>>>(pooled, batch, W1, b1, W2, b2, out);
}

// Round 11
// 824.356 us; speedup vs baseline: 1.1486x; 1.1486x over previous
//
#include <hip/hip_runtime.h>
#include <hip/hip_bf16.h>
#include <math.h>

#define N_NODES 50000
#define N_EDGES 800000
#define FEAT 90
#define HD 128
#define STEPS 4
#define N_GRAPHS 100
#define SCAN_BLOCKS 196  // 196*256 = 50176 >= 50000
#define GRU_ROWS 128

typedef __attribute__((ext_vector_type(8))) short short8v;
typedef __attribute__((ext_vector_type(8))) unsigned int uint8v;
typedef __attribute__((ext_vector_type(4))) float f32x4;
typedef unsigned short ushort_t;
typedef unsigned int uint_t;

__device__ __forceinline__ float sigmoid_(float x) { return 1.f / (1.f + expf(-x)); }

__device__ __forceinline__ ushort_t f2bf(float x) {
    uint_t u = __float_as_uint(x);
    uint_t r = (u + 0x7fffu + ((u >> 16) & 1u)) >> 16;   // RNE
    return (ushort_t)r;
}
__device__ __forceinline__ float bf2f(ushort_t h) { return __uint_as_float(((uint_t)h) << 16); }
// packed element: (hi16 << 16) | lo16 ; value = f(hi) + f(lo)
__device__ __forceinline__ uint_t packf(float x) {
    ushort_t hi = f2bf(x);
    ushort_t lo = f2bf(x - bf2f(hi));
    return ((uint_t)hi << 16) | lo;
}
__device__ __forceinline__ float unpackf(uint_t u) {
    return __uint_as_float(u & 0xffff0000u) + __uint_as_float(u << 16);
}

__device__ __forceinline__ f32x4 mfma16(short8v a, short8v b, f32x4 c) {
    return __builtin_amdgcn_mfma_f32_16x16x32_bf16(a, b, c, 0, 0, 0);
}

// async global->LDS, 16B per lane; LDS dest = wave-uniform base + lane*16
__device__ __forceinline__ void gload_lds16(const void* g, void* l) {
    __builtin_amdgcn_global_load_lds(
        (const __attribute__((address_space(1))) unsigned int*)g,
        (__attribute__((address_space(3))) unsigned int*)l,
        16, 0, 0);
}

// ---------------- CSR build ----------------
__global__ void k_count(const int* __restrict__ dst, int* __restrict__ deg) {
    int e = blockIdx.x * 256 + threadIdx.x;
    if (e < N_EDGES) atomicAdd(&deg[dst[e]], 1);
}

// phase 1: per-block sums of deg (coalesced)
__global__ __launch_bounds__(256) void k_bsum(const int* __restrict__ deg,
                                              int* __restrict__ bsum) {
    int t = threadIdx.x, b = blockIdx.x;
    int v = b * 256 + t;
    int x = (v < N_NODES) ? deg[v] : 0;
#pragma unroll
    for (int off = 32; off > 0; off >>= 1) x += __shfl_down(x, off, 64);
    __shared__ int ws[4];
    if ((t & 63) == 0) ws[t >> 6] = x;
    __syncthreads();
    if (t == 0) bsum[b] = ws[0] + ws[1] + ws[2] + ws[3];
}

// phase 2: exclusive scan of the 196 block sums (single tiny block)
__global__ __launch_bounds__(256) void k_bscan(const int* __restrict__ bsum,
                                               int* __restrict__ bpre) {
    __shared__ int s[256];
    int t = threadIdx.x;
    int x = (t < SCAN_BLOCKS) ? bsum[t] : 0;
    s[t] = x;
    __syncthreads();
    for (int off = 1; off < 256; off <<= 1) {
        int y = (t >= off) ? s[t - off] : 0;
        __syncthreads();
        s[t] += y;
        __syncthreads();
    }
    if (t < SCAN_BLOCKS) bpre[t] = s[t] - x;
}

// phase 3: per-block 256-wide scan + block prefix, coalesced writes
__global__ __launch_bounds__(256) void k_wscan(const int* __restrict__ deg,
                                               const int* __restrict__ bpre,
                                               int* __restrict__ row_start,
                                               int* __restrict__ cursor) {
    __shared__ int s[256];
    int t = threadIdx.x, b = blockIdx.x;
    int v = b * 256 + t;
    int x = (v < N_NODES) ? deg[v] : 0;
    s[t] = x;
    __syncthreads();
    for (int off = 1; off < 256; off <<= 1) {
        int y = (t >= off) ? s[t - off] : 0;
        __syncthreads();
        s[t] += y;
        __syncthreads();
    }
    int excl = bpre[b] + s[t] - x;
    if (v < N_NODES) { row_start[v] = excl; cursor[v] = excl; }
    if (b == 0 && t == 0) row_start[N_NODES] = N_EDGES;  // all dst are valid nodes
}

__global__ void k_fill(const int* __restrict__ src, const int* __restrict__ dst,
                       int* __restrict__ cursor, int* __restrict__ esrc) {
    int e = blockIdx.x * 256 + threadIdx.x;
    if (e < N_EDGES) {
        int p = atomicAdd(&cursor[dst[e]], 1);
        esrc[p] = src[e];
    }
}

// ---------------- Wmi[i] = W_msg[i] @ W_ih  (f32, [4][128][384]) ----------------
__global__ __launch_bounds__(128) void k_wmi(const float* __restrict__ Wmsg,
                                             const float* __restrict__ Wih,
                                             float* __restrict__ Wmi) {
    int b = blockIdx.x;              // ((i*128)+r)*3 + cc
    int cc = b % 3;
    int ir = b / 3;
    int r = ir % 128, i = ir / 128;
    int c = cc * 128 + threadIdx.x;
    __shared__ float wrow[128];
    wrow[threadIdx.x] = Wmsg[((size_t)i * 128 + r) * 128 + threadIdx.x];
    __syncthreads();
    float acc = 0.f;
#pragma unroll 8
    for (int k = 0; k < 128; ++k) acc += wrow[k] * Wih[(size_t)k * 384 + c];
    Wmi[((size_t)i * 128 + r) * 384 + c] = acc;
}

// ---------------- pack B [128][384] f32 -> fragment-order split bf16 ----------------
// frag addressing: hi/lo[(((sl*24 + t)*64 + lane)*8 + j]
//   covers B[sl*32 + (lane>>4)*8 + j][t*16 + (lane&15)]
__global__ __launch_bounds__(256) void k_packB(const float* __restrict__ Wmi,
                                               const float* __restrict__ Whh,
                                               ushort_t* __restrict__ BmHi, ushort_t* __restrict__ BmLo,
                                               ushort_t* __restrict__ BhHi, ushort_t* __restrict__ BhLo) {
    int y = blockIdx.y;  // 0..3 -> Wmi step y ; 4 -> Whh
    const float* W;
    ushort_t *dhi, *dlo;
    if (y < 4) { W = Wmi + (size_t)y * 49152; dhi = BmHi + (size_t)y * 49152; dlo = BmLo + (size_t)y * 49152; }
    else       { W = Whh;                     dhi = BhHi;                     dlo = BhLo; }
    int g = blockIdx.x * 256 + threadIdx.x;   // 0..6143
    int lane = g & 63;
    int tt = (g >> 6) % 24;
    int sl = (g >> 6) / 24;
    int kb = sl * 32 + (lane >> 4) * 8;
    int c = tt * 16 + (lane & 15);
    short8v h8, l8;
#pragma unroll
    for (int j = 0; j < 8; ++j) {
        float w = W[(size_t)(kb + j) * 384 + c];
        ushort_t hi = f2bf(w);
        ushort_t lo = f2bf(w - bf2f(hi));
        h8[j] = (short)hi;
        l8[j] = (short)lo;
    }
    size_t o = (((size_t)sl * 24 + tt) * 64 + lane) * 8;
    *(short8v*)&dhi[o] = h8;
    *(short8v*)&dlo[o] = l8;
}

// ---------------- Embedding: h = relu(x @ Wemb) -> packed split bf16 ----------------
__global__ __launch_bounds__(256) void k_embed(const float* __restrict__ x,
                                               const float* __restrict__ Wemb,
                                               uint_t* __restrict__ hp) {
    __shared__ __align__(16) float a_s[32 * 96];
    __shared__ __align__(16) float w_s[96 * 128];
    int t = threadIdx.x;
    int n0 = blockIdx.x * 32;
    for (int i = t; i < 96 * 128; i += 256) {
        int k = i >> 7;
        w_s[i] = (k < FEAT) ? Wemb[i] : 0.f;
    }
    for (int i = t; i < 32 * 96; i += 256) {
        int r = i / 96, k = i - r * 96;
        int n = n0 + r;
        a_s[i] = (k < FEAT && n < N_NODES) ? x[(size_t)n * FEAT + k] : 0.f;
    }
    __syncthreads();
    int tx = t & 63, rg = t >> 6;
    float acc[8][2];
#pragma unroll
    for (int r = 0; r < 8; ++r) { acc[r][0] = 0.f; acc[r][1] = 0.f; }
    for (int k0 = 0; k0 < 96; k0 += 4) {
        float a4[8][4];
#pragma unroll
        for (int r = 0; r < 8; ++r)
            *(float4*)a4[r] = *(const float4*)&a_s[(rg * 8 + r) * 96 + k0];
#pragma unroll
        for (int j = 0; j < 4; ++j) {
            float w0 = w_s[(k0 + j) * 128 + tx];
            float w1 = w_s[(k0 + j) * 128 + tx + 64];
#pragma unroll
            for (int r = 0; r < 8; ++r) {
                acc[r][0] += a4[r][j] * w0;
                acc[r][1] += a4[r][j] * w1;
            }
        }
    }
#pragma unroll
    for (int r = 0; r < 8; ++r) {
        int n = n0 + rg * 8 + r;
        if (n < N_NODES) {
            size_t o = (size_t)n * HD + tx;
            hp[o]      = packf(fmaxf(acc[r][0], 0.f));
            hp[o + 64] = packf(fmaxf(acc[r][1], 0.f));
        }
    }
}

// ---------------- gather: agg[v] = sum_{e in CSR[v]} h[src_e]  (packed in/out) ----------------
__global__ __launch_bounds__(256) void k_gather(const uint_t* __restrict__ hp,
                                                const int* __restrict__ row_start,
                                                const int* __restrict__ esrc,
                                                uint_t* __restrict__ aggp) {
    int lane = threadIdx.x & 63;
    int wid = threadIdx.x >> 6;
    int v = blockIdx.x * 4 + wid;           // 50000 = 12500*4 exact
    int beg = row_start[v], end = row_start[v + 1];
    int off = lane * 2;
    float a0 = 0.f, a1 = 0.f;
    int j = beg;
    for (; j + 4 <= end; j += 4) {
        int s0 = esrc[j], s1 = esrc[j + 1], s2 = esrc[j + 2], s3 = esrc[j + 3];
        uint2 u0 = *(const uint2*)&hp[(size_t)s0 * HD + off];
        uint2 u1 = *(const uint2*)&hp[(size_t)s1 * HD + off];
        uint2 u2 = *(const uint2*)&hp[(size_t)s2 * HD + off];
        uint2 u3 = *(const uint2*)&hp[(size_t)s3 * HD + off];
        a0 += unpackf(u0.x) + unpackf(u1.x) + unpackf(u2.x) + unpackf(u3.x);
        a1 += unpackf(u0.y) + unpackf(u1.y) + unpackf(u2.y) + unpackf(u3.y);
    }
    for (; j + 2 <= end; j += 2) {
        int s0 = esrc[j], s1 = esrc[j + 1];
        uint2 u0 = *(const uint2*)&hp[(size_t)s0 * HD + off];
        uint2 u1 = *(const uint2*)&hp[(size_t)s1 * HD + off];
        a0 += unpackf(u0.x) + unpackf(u1.x);
        a1 += unpackf(u0.y) + unpackf(u1.y);
    }
    if (j < end) {
        uint2 u0 = *(const uint2*)&hp[(size_t)esrc[j] * HD + off];
        a0 += unpackf(u0.x);
        a1 += unpackf(u0.y);
    }
    *(uint2*)&aggp[(size_t)v * HD + off] = make_uint2(packf(a0), packf(a1));
}

// ---------------- fused GRU via MFMA, async global_load_lds double-buffered staging ----------------
// gates[N,384] = [agg | h] @ [Wmi ; Whh], split-bf16 3-term MFMA, in-register epilogue.
// block: 512 thr = 8 waves (wr row-group, wc col-half), tile 128 rows.
// 16 phases = (k-group 0..7) x (hi/lo half); 24KB per phase, 2x24KB ping-pong via global_load_lds.
// launch_bounds(512,2): 256-reg unified cap -> acc lives in AGPR/VGPR, NO scratch spill.
__global__ __launch_bounds__(512, 2) void k_gru_mfma(const uint_t* __restrict__ aggp,
                                                     uint_t* __restrict__ hp,
                                                     const ushort_t* __restrict__ BmHi,
                                                     const ushort_t* __restrict__ BmLo,
                                                     const ushort_t* __restrict__ BhHi,
                                                     const ushort_t* __restrict__ BhLo,
                                                     const float* __restrict__ bih,
                                                     const float* __restrict__ bhh) {
    __shared__ __align__(16) ushort_t bsm[2][12288];  // 2 x 24KB half-slice buffers
    int t = threadIdx.x;          // 0..511
    int lane = t & 63;
    int wid = t >> 6;             // 0..7
    int wr = wid >> 1, wc = wid & 1;
    int row_base = blockIdx.x * GRU_ROWS + wr * 32;
    int ar0 = min(row_base + (lane & 15), N_NODES - 1);
    int ar1 = min(row_base + 16 + (lane & 15), N_NODES - 1);
    int kcol = (lane >> 4) * 8;

    f32x4 accR[2][4], accZ[2][4], accXN[2][4], accHN[2][4];
#pragma unroll
    for (int rf = 0; rf < 2; ++rf)
#pragma unroll
        for (int q = 0; q < 4; ++q) {
            accR[rf][q] = (f32x4)0.f; accZ[rf][q] = (f32x4)0.f;
            accXN[rf][q] = (f32x4)0.f; accHN[rf][q] = (f32x4)0.f;
        }

    // stage phase pp's 24KB half-slice into bsm[pp&1] via async global_load_lds.
    // wave w copies 3 x 1KB chunks: lds base wave-uniform, global addr per-lane.
    auto stage = [&](int pp) {
        const int k2 = pp >> 1, half2 = pp & 1;
        const ushort_t* base = (k2 >> 2) ? (half2 ? BhLo : BhHi) : (half2 ? BmLo : BmHi);
        const uint4* g = (const uint4*)(base + (size_t)(k2 & 3) * 12288);
        uint4* d = (uint4*)bsm[pp & 1];
        const int cb = wid << 6;   // wave chunk base, uint4 units
#pragma unroll
        for (int i = 0; i < 3; ++i)
            gload_lds16(&g[cb + i * 512 + lane], &d[cb + i * 512]);
    };

    // prologue: A for group 0 + stage phase 0
    uint8v u0 = *(const uint8v*)&aggp[(size_t)ar0 * HD + kcol];
    uint8v u1 = *(const uint8v*)&aggp[(size_t)ar1 * HD + kcol];
    stage(0);
    __syncthreads();

#pragma unroll
    for (int k = 0; k < 8; ++k) {
        const int src = k >> 2;       // 0: agg/Wmi, 1: h/Whh
        // extract A fragments once per group (live across hi+lo)
        short8v a0h, a0l, a1h, a1l;
#pragma unroll
        for (int j = 0; j < 8; ++j) {
            a0h[j] = (short)(u0[j] >> 16); a0l[j] = (short)(u0[j] & 0xffffu);
            a1h[j] = (short)(u1[j] >> 16); a1l[j] = (short)(u1[j] & 0xffffu);
        }
        // ---- hi phase (reads bsm[0]): 2 terms Ah*Bh + Al*Bh ----
        stage(2 * k + 1);
        {
            const ushort_t* bb = bsm[0];
#pragma unroll
            for (int grp = 0; grp < 3; ++grp) {
                auto& gate = (grp == 0) ? accR : (grp == 1) ? accZ : (src == 0) ? accXN : accHN;
#pragma unroll
                for (int q = 0; q < 4; ++q) {
                    int tt = grp * 8 + wc * 4 + q;
                    short8v b = *(const short8v*)&bb[(tt * 64 + lane) * 8];
                    gate[0][q] = mfma16(a0h, b, gate[0][q]);
                    gate[0][q] = mfma16(a0l, b, gate[0][q]);
                    gate[1][q] = mfma16(a1h, b, gate[1][q]);
                    gate[1][q] = mfma16(a1l, b, gate[1][q]);
                }
            }
        }
        __syncthreads();
        // ---- lo phase (reads bsm[1]): 1 term Ah*Bl ----
        if (k < 7) {
            const uint_t* Ap2 = ((k + 1) >> 2) ? hp : aggp;
            const int kb2 = ((k + 1) & 3) * 32 + kcol;
            u0 = *(const uint8v*)&Ap2[(size_t)ar0 * HD + kb2];
            u1 = *(const uint8v*)&Ap2[(size_t)ar1 * HD + kb2];
            stage(2 * k + 2);
        }
        {
            const ushort_t* bb = bsm[1];
#pragma unroll
            for (int grp = 0; grp < 3; ++grp) {
                auto& gate = (grp == 0) ? accR : (grp == 1) ? accZ : (src == 0) ? accXN : accHN;
#pragma unroll
                for (int q = 0; q < 4; ++q) {
                    int tt = grp * 8 + wc * 4 + q;
                    short8v b = *(const short8v*)&bb[(tt * 64 + lane) * 8];
                    gate[0][q] = mfma16(a0h, b, gate[0][q]);
                    gate[1][q] = mfma16(a1h, b, gate[1][q]);
                }
            }
        }
        __syncthreads();
    }

#pragma unroll
    for (int rf = 0; rf < 2; ++rf) {
#pragma unroll
        for (int q = 0; q < 4; ++q) {
            int c = wc * 64 + q * 16 + (lane & 15);
            float bir = bih[c],       bhr = bhh[c];
            float biz = bih[c + 128], bhz = bhh[c + 128];
            float bin_ = bih[c + 256], bhn = bhh[c + 256];
#pragma unroll
            for (int j = 0; j < 4; ++j) {
                int row = row_base + rf * 16 + ((lane >> 4) << 2) + j;
                if (row < N_NODES) {
                    float rr = sigmoid_(accR[rf][q][j] + bir + bhr);
                    float zz = sigmoid_(accZ[rf][q][j] + biz + bhz);
                    float nn = tanhf(accXN[rf][q][j] + bin_ + rr * (accHN[rf][q][j] + bhn));
                    size_t idx = (size_t)row * HD + c;
                    float hold = unpackf(hp[idx]);
                    hp[idx] = packf((1.f - zz) * nn + zz * hold);
                }
            }
        }
    }
}

// ---------------- pooling ----------------
#define POOL_CHUNK 256
__global__ __launch_bounds__(128) void k_pool(const uint_t* __restrict__ hp,
                                              const int* __restrict__ batch,
                                              float* __restrict__ pooled) {
    int t = threadIdx.x;  // 128 cols
    int n0 = blockIdx.x * POOL_CHUNK;
    int nend = n0 + POOL_CHUNK;
    if (nend > N_NODES) nend = N_NODES;
    float acc = 0.f;
    int cur = batch[n0];
    for (int n = n0; n < nend; ++n) {
        int g = batch[n];
        if (g != cur) {
            atomicAdd(&pooled[(size_t)cur * HD + t], acc);
            acc = 0.f;
            cur = g;
        }
        acc += fmaxf(unpackf(hp[(size_t)n * HD + t]), 0.f);  // fused final relu
    }
    atomicAdd(&pooled[(size_t)cur * HD + t], acc);
}

// ---------------- output MLP (counts via binary search on sorted batch) ----------------
__global__ __launch_bounds__(128) void k_out(const float* __restrict__ pooled,
                                             const int* __restrict__ batch,
                                             const float* __restrict__ W1,
                                             const float* __restrict__ b1,
                                             const float* __restrict__ W2,
                                             const float* __restrict__ b2,
                                             float* __restrict__ out) {
    __shared__ float row[128];
    __shared__ float red[128];
    int t = threadIdx.x;
    int g = blockIdx.x;
    int lo0 = 0, hi0 = N_NODES;
    while (lo0 < hi0) { int mid = (lo0 + hi0) >> 1; if (batch[mid] < g) lo0 = mid + 1; else hi0 = mid; }
    int lo1 = lo0, hi1 = N_NODES;
    while (lo1 < hi1) { int mid = (lo1 + hi1) >> 1; if (batch[mid] < g + 1) lo1 = mid + 1; else hi1 = mid; }
    float cnt = (float)(lo1 - lo0);
    if (cnt < 1.f) cnt = 1.f;
    row[t] = pooled[(size_t)g * HD + t] / cnt;
    __syncthreads();
    float acc = b1[t];
#pragma unroll 4
    for (int k = 0; k < HD; ++k) acc += row[k] * W1[k * HD + t];
    float hv = fmaxf(acc, 0.f);
    red[t] = hv * W2[t];
    __syncthreads();
    for (int off = 64; off > 0; off >>= 1) {
        if (t < off) red[t] += red[t + off];
        __syncthreads();
    }
    if (t == 0) {
        float xv = red[0] + b2[0];
        out[g] = fmaxf(xv, 0.f) + log1pf(expf(-fabsf(xv)));
    }
}

extern "C" void kernel_launch(void* const* d_in, const int* in_sizes, int n_in,
                              void* d_out, int out_size, void* d_ws, size_t ws_size,
                              hipStream_t stream) {
    (void)in_sizes; (void)n_in; (void)out_size; (void)ws_size;
    const float* x    = (const float*)d_in[0];
    const int*   ei   = (const int*)d_in[1];
    const int*   batch= (const int*)d_in[2];
    const float* Wemb = (const float*)d_in[3];
    const float* Wmsg = (const float*)d_in[4];
    const float* Wih  = (const float*)d_in[5];
    const float* Whh  = (const float*)d_in[6];
    const float* bih  = (const float*)d_in[7];
    const float* bhh  = (const float*)d_in[8];
    const float* W1   = (const float*)d_in[9];
    const float* b1   = (const float*)d_in[10];
    const float* W2   = (const float*)d_in[11];
    const float* b2   = (const float*)d_in[12];
    float* out = (float*)d_out;

    const int* e_src = ei;
    const int* e_dst = ei + N_EDGES;

    char* ws = (char*)d_ws;
    size_t off = 0;
    auto alloc = [&](size_t bytes) -> void* {
        void* p = ws + off;
        off = (off + bytes + 255) & ~(size_t)255;
        return p;
    };
    uint_t* hp       = (uint_t*)alloc((size_t)N_NODES * HD * 4);
    uint_t* aggp     = (uint_t*)alloc((size_t)N_NODES * HD * 4);
    float* Wmi       = (float*)alloc((size_t)STEPS * 128 * 384 * 4);
    ushort_t* BmHi   = (ushort_t*)alloc((size_t)STEPS * 128 * 384 * 2);
    ushort_t* BmLo   = (ushort_t*)alloc((size_t)STEPS * 128 * 384 * 2);
    ushort_t* BhHi   = (ushort_t*)alloc((size_t)128 * 384 * 2);
    ushort_t* BhLo   = (ushort_t*)alloc((size_t)128 * 384 * 2);
    float* pooled    = (float*)alloc((size_t)N_GRAPHS * HD * 4);
    int* deg         = (int*)alloc((size_t)N_NODES * 4);
    int* row_start   = (int*)alloc((size_t)(N_NODES + 1) * 4);
    int* cursor      = (int*)alloc((size_t)N_NODES * 4);
    int* esrc        = (int*)alloc((size_t)N_EDGES * 4);
    int* bsum        = (int*)alloc((size_t)SCAN_BLOCKS * 4);
    int* bpre        = (int*)alloc((size_t)SCAN_BLOCKS * 4);

    hipMemsetAsync(deg, 0, (size_t)N_NODES * 4, stream);
    hipMemsetAsync(pooled, 0, (size_t)N_GRAPHS * HD * 4, stream);

    k_count<<<(N_EDGES + 255) / 256, 256, 0, stream>>>(e_dst, deg);
    k_bsum<<<SCAN_BLOCKS, 256, 0, stream>>>(deg, bsum);
    k_bscan<<<1, 256, 0, stream>>>(bsum, bpre);
    k_wscan<<<SCAN_BLOCKS, 256, 0, stream>>>(deg, bpre, row_start, cursor);
    k_fill<<<(N_EDGES + 255) / 256, 256, 0, stream>>>(e_src, e_dst, cursor, esrc);

    k_wmi<<<STEPS * 128 * 3, 128, 0, stream>>>(Wmsg, Wih, Wmi);
    k_packB<<<dim3(24, 5), 256, 0, stream>>>(Wmi, Whh, BmHi, BmLo, BhHi, BhLo);

    k_embed<<<(N_NODES + 31) / 32, 256, 0, stream>>>(x, Wemb, hp);

    for (int i = 0; i < STEPS; ++i) {
        k_gather<<<N_NODES / 4, 256, 0, stream>>>(hp, row_start, esrc, aggp);
        k_gru_mfma<<<(N_NODES + GRU_ROWS - 1) / GRU_ROWS, 512, 0, stream>>>(
            aggp, hp,
            BmHi + (size_t)i * 49152, BmLo + (size_t)i * 49152,
            BhHi, BhLo, bih, bhh);
    }

    k_pool<<<(N_NODES + POOL_CHUNK - 1) / POOL_CHUNK, 128, 0, stream>>>(hp, batch, pooled);
    k_out<<<N_GRAPHS, 128, 0, stream>>>(pooled, batch, W1, b1, W2, b2, out);
}

// Round 13
// 764.739 us; speedup vs baseline: 1.2382x; 1.0780x over previous
//
#include <hip/hip_runtime.h>
#include <hip/hip_bf16.h>
#include <math.h>

#define N_NODES 50000
#define N_EDGES 800000
#define FEAT 90
#define HD 128
#define STEPS 4
#define N_GRAPHS 100
#define SCAN_BLOCKS 196  // 196*256 = 50176 >= 50000
#define GRU_ROWS 128
#define EMB_TILES ((N_NODES + 31) / 32)

typedef __attribute__((ext_vector_type(8))) short short8v;
typedef __attribute__((ext_vector_type(8))) unsigned int uint8v;
typedef __attribute__((ext_vector_type(4))) float f32x4;
typedef unsigned short ushort_t;
typedef unsigned int uint_t;

__device__ __forceinline__ float sigmoid_(float x) { return 1.f / (1.f + expf(-x)); }

__device__ __forceinline__ ushort_t f2bf(float x) {
    uint_t u = __float_as_uint(x);
    uint_t r = (u + 0x7fffu + ((u >> 16) & 1u)) >> 16;   // RNE
    return (ushort_t)r;
}
__device__ __forceinline__ float bf2f(ushort_t h) { return __uint_as_float(((uint_t)h) << 16); }
// packed element: (hi16 << 16) | lo16 ; value = f(hi) + f(lo)
__device__ __forceinline__ uint_t packf(float x) {
    ushort_t hi = f2bf(x);
    ushort_t lo = f2bf(x - bf2f(hi));
    return ((uint_t)hi << 16) | lo;
}
__device__ __forceinline__ float unpackf(uint_t u) {
    return __uint_as_float(u & 0xffff0000u) + __uint_as_float(u << 16);
}

__device__ __forceinline__ f32x4 mfma16(short8v a, short8v b, f32x4 c) {
    return __builtin_amdgcn_mfma_f32_16x16x32_bf16(a, b, c, 0, 0, 0);
}

// async global->LDS, 16B per lane; LDS dest = wave-uniform base + lane*16
__device__ __forceinline__ void gload_lds16(const void* g, void* l) {
    __builtin_amdgcn_global_load_lds(
        (const __attribute__((address_space(1))) unsigned int*)g,
        (__attribute__((address_space(3))) unsigned int*)l,
        16, 0, 0);
}

// ---------------- CSR build ----------------
__global__ void k_count(const int* __restrict__ dst, int* __restrict__ deg) {
    int e = blockIdx.x * 256 + threadIdx.x;
    if (e < N_EDGES) atomicAdd(&deg[dst[e]], 1);
}

// phase 1: per-block sums of deg (coalesced)
__global__ __launch_bounds__(256) void k_bsum(const int* __restrict__ deg,
                                              int* __restrict__ bsum) {
    int t = threadIdx.x, b = blockIdx.x;
    int v = b * 256 + t;
    int x = (v < N_NODES) ? deg[v] : 0;
#pragma unroll
    for (int off = 32; off > 0; off >>= 1) x += __shfl_down(x, off, 64);
    __shared__ int ws[4];
    if ((t & 63) == 0) ws[t >> 6] = x;
    __syncthreads();
    if (t == 0) bsum[b] = ws[0] + ws[1] + ws[2] + ws[3];
}

// phase 2: exclusive scan of the 196 block sums (single tiny block)
__global__ __launch_bounds__(256) void k_bscan(const int* __restrict__ bsum,
                                               int* __restrict__ bpre) {
    __shared__ int s[256];
    int t = threadIdx.x;
    int x = (t < SCAN_BLOCKS) ? bsum[t] : 0;
    s[t] = x;
    __syncthreads();
    for (int off = 1; off < 256; off <<= 1) {
        int y = (t >= off) ? s[t - off] : 0;
        __syncthreads();
        s[t] += y;
        __syncthreads();
    }
    if (t < SCAN_BLOCKS) bpre[t] = s[t] - x;
}

// phase 3: per-block 256-wide scan + block prefix, coalesced writes
__global__ __launch_bounds__(256) void k_wscan(const int* __restrict__ deg,
                                               const int* __restrict__ bpre,
                                               int* __restrict__ row_start,
                                               int* __restrict__ cursor) {
    __shared__ int s[256];
    int t = threadIdx.x, b = blockIdx.x;
    int v = b * 256 + t;
    int x = (v < N_NODES) ? deg[v] : 0;
    s[t] = x;
    __syncthreads();
    for (int off = 1; off < 256; off <<= 1) {
        int y = (t >= off) ? s[t - off] : 0;
        __syncthreads();
        s[t] += y;
        __syncthreads();
    }
    int excl = bpre[b] + s[t] - x;
    if (v < N_NODES) { row_start[v] = excl; cursor[v] = excl; }
    if (b == 0 && t == 0) row_start[N_NODES] = N_EDGES;  // all dst are valid nodes
}

__global__ void k_fill(const int* __restrict__ src, const int* __restrict__ dst,
                       int* __restrict__ cursor, int* __restrict__ esrc) {
    int e = blockIdx.x * 256 + threadIdx.x;
    if (e < N_EDGES) {
        int p = atomicAdd(&cursor[dst[e]], 1);
        esrc[p] = src[e];
    }
}

// ---------------- Wmi[i] = W_msg[i] @ W_ih  (f32, [4][128][384]) ----------------
__global__ __launch_bounds__(128) void k_wmi(const float* __restrict__ Wmsg,
                                             const float* __restrict__ Wih,
                                             float* __restrict__ Wmi) {
    int b = blockIdx.x;              // ((i*128)+r)*3 + cc
    int cc = b % 3;
    int ir = b / 3;
    int r = ir % 128, i = ir / 128;
    int c = cc * 128 + threadIdx.x;
    __shared__ float wrow[128];
    wrow[threadIdx.x] = Wmsg[((size_t)i * 128 + r) * 128 + threadIdx.x];
    __syncthreads();
    float acc = 0.f;
#pragma unroll 8
    for (int k = 0; k < 128; ++k) acc += wrow[k] * Wih[(size_t)k * 384 + c];
    Wmi[((size_t)i * 128 + r) * 384 + c] = acc;
}

// ---------------- pack B [128][384] f32 -> fragment-order split bf16 ----------------
// frag addressing: hi/lo[(((sl*24 + t)*64 + lane)*8 + j]
//   covers B[sl*32 + (lane>>4)*8 + j][t*16 + (lane&15)]
__global__ __launch_bounds__(256) void k_packB(const float* __restrict__ Wmi,
                                               const float* __restrict__ Whh,
                                               ushort_t* __restrict__ BmHi, ushort_t* __restrict__ BmLo,
                                               ushort_t* __restrict__ BhHi, ushort_t* __restrict__ BhLo) {
    int y = blockIdx.y;  // 0..3 -> Wmi step y ; 4 -> Whh
    const float* W;
    ushort_t *dhi, *dlo;
    if (y < 4) { W = Wmi + (size_t)y * 49152; dhi = BmHi + (size_t)y * 49152; dlo = BmLo + (size_t)y * 49152; }
    else       { W = Whh;                     dhi = BhHi;                     dlo = BhLo; }
    int g = blockIdx.x * 256 + threadIdx.x;   // 0..6143
    int lane = g & 63;
    int tt = (g >> 6) % 24;
    int sl = (g >> 6) / 24;
    int kb = sl * 32 + (lane >> 4) * 8;
    int c = tt * 16 + (lane & 15);
    short8v h8, l8;
#pragma unroll
    for (int j = 0; j < 8; ++j) {
        float w = W[(size_t)(kb + j) * 384 + c];
        ushort_t hi = f2bf(w);
        ushort_t lo = f2bf(w - bf2f(hi));
        h8[j] = (short)hi;
        l8[j] = (short)lo;
    }
    size_t o = (((size_t)sl * 24 + tt) * 64 + lane) * 8;
    *(short8v*)&dhi[o] = h8;
    *(short8v*)&dlo[o] = l8;
}

// ---------------- Embedding: h = relu(x @ Wemb) -> packed split bf16 ----------------
// persistent-W grid-stride: each block stages Wemb ONCE, then loops over 32-row tiles.
__global__ __launch_bounds__(256) void k_embed(const float* __restrict__ x,
                                               const float* __restrict__ Wemb,
                                               uint_t* __restrict__ hp) {
    __shared__ __align__(16) float w_s[96 * 128];
    __shared__ __align__(16) float a_s[32 * 96];
    int t = threadIdx.x;
    for (int i = t; i < 96 * 128; i += 256) {
        int k = i >> 7;
        w_s[i] = (k < FEAT) ? Wemb[i] : 0.f;
    }
    int tx = t & 63, rg = t >> 6;
    for (int tile = blockIdx.x; tile < EMB_TILES; tile += gridDim.x) {
        int n0 = tile * 32;
        __syncthreads();  // first iter: w_s ready; later: prev tile's a_s consumers done
        for (int i = t; i < 32 * 96; i += 256) {
            int r = i / 96, k = i - r * 96;
            int n = n0 + r;
            a_s[i] = (k < FEAT && n < N_NODES) ? x[(size_t)n * FEAT + k] : 0.f;
        }
        __syncthreads();
        float acc[8][2];
#pragma unroll
        for (int r = 0; r < 8; ++r) { acc[r][0] = 0.f; acc[r][1] = 0.f; }
        for (int k0 = 0; k0 < 96; k0 += 4) {
            float a4[8][4];
#pragma unroll
            for (int r = 0; r < 8; ++r)
                *(float4*)a4[r] = *(const float4*)&a_s[(rg * 8 + r) * 96 + k0];
#pragma unroll
            for (int j = 0; j < 4; ++j) {
                float w0 = w_s[(k0 + j) * 128 + tx];
                float w1 = w_s[(k0 + j) * 128 + tx + 64];
#pragma unroll
                for (int r = 0; r < 8; ++r) {
                    acc[r][0] += a4[r][j] * w0;
                    acc[r][1] += a4[r][j] * w1;
                }
            }
        }
#pragma unroll
        for (int r = 0; r < 8; ++r) {
            int n = n0 + rg * 8 + r;
            if (n < N_NODES) {
                size_t o = (size_t)n * HD + tx;
                hp[o]      = packf(fmaxf(acc[r][0], 0.f));
                hp[o + 64] = packf(fmaxf(acc[r][1], 0.f));
            }
        }
    }
}

// ---------------- gather: agg[v] = sum_{e in CSR[v]} h[src_e]  (packed in/out) ----------------
__global__ __launch_bounds__(256) void k_gather(const uint_t* __restrict__ hp,
                                                const int* __restrict__ row_start,
                                                const int* __restrict__ esrc,
                                                uint_t* __restrict__ aggp) {
    int lane = threadIdx.x & 63;
    int wid = threadIdx.x >> 6;
    int v = blockIdx.x * 4 + wid;           // 50000 = 12500*4 exact
    int beg = row_start[v], end = row_start[v + 1];
    int off = lane * 2;
    float a0 = 0.f, a1 = 0.f;
    int j = beg;
    for (; j + 4 <= end; j += 4) {
        int s0 = esrc[j], s1 = esrc[j + 1], s2 = esrc[j + 2], s3 = esrc[j + 3];
        uint2 u0 = *(const uint2*)&hp[(size_t)s0 * HD + off];
        uint2 u1 = *(const uint2*)&hp[(size_t)s1 * HD + off];
        uint2 u2 = *(const uint2*)&hp[(size_t)s2 * HD + off];
        uint2 u3 = *(const uint2*)&hp[(size_t)s3 * HD + off];
        a0 += unpackf(u0.x) + unpackf(u1.x) + unpackf(u2.x) + unpackf(u3.x);
        a1 += unpackf(u0.y) + unpackf(u1.y) + unpackf(u2.y) + unpackf(u3.y);
    }
    for (; j + 2 <= end; j += 2) {
        int s0 = esrc[j], s1 = esrc[j + 1];
        uint2 u0 = *(const uint2*)&hp[(size_t)s0 * HD + off];
        uint2 u1 = *(const uint2*)&hp[(size_t)s1 * HD + off];
        a0 += unpackf(u0.x) + unpackf(u1.x);
        a1 += unpackf(u0.y) + unpackf(u1.y);
    }
    if (j < end) {
        uint2 u0 = *(const uint2*)&hp[(size_t)esrc[j] * HD + off];
        a0 += unpackf(u0.x);
        a1 += unpackf(u0.y);
    }
    *(uint2*)&aggp[(size_t)v * HD + off] = make_uint2(packf(a0), packf(a1));
}

// ---------------- fused GRU via MFMA, async global_load_lds double-buffered staging ----------------
// gates[N,384] = [agg | h] @ [Wmi ; Whh], split-bf16 3-term MFMA, in-register epilogue.
// block: 512 thr = 8 waves (wr row-group, wc col-half), tile 128 rows.
// 16 phases = (k-group 0..7) x (hi/lo half); 24KB per phase, 2x24KB ping-pong via global_load_lds.
// launch_bounds(512,2): 256-reg unified cap -> acc lives in AGPR/VGPR, NO scratch spill.
__global__ __launch_bounds__(512, 2) void k_gru_mfma(const uint_t* __restrict__ aggp,
                                                     uint_t* __restrict__ hp,
                                                     const ushort_t* __restrict__ BmHi,
                                                     const ushort_t* __restrict__ BmLo,
                                                     const ushort_t* __restrict__ BhHi,
                                                     const ushort_t* __restrict__ BhLo,
                                                     const float* __restrict__ bih,
                                                     const float* __restrict__ bhh) {
    __shared__ __align__(16) ushort_t bsm[2][12288];  // 2 x 24KB half-slice buffers
    int t = threadIdx.x;          // 0..511
    int lane = t & 63;
    int wid = t >> 6;             // 0..7
    int wr = wid >> 1, wc = wid & 1;
    int row_base = blockIdx.x * GRU_ROWS + wr * 32;
    int ar0 = min(row_base + (lane & 15), N_NODES - 1);
    int ar1 = min(row_base + 16 + (lane & 15), N_NODES - 1);
    int kcol = (lane >> 4) * 8;

    f32x4 accR[2][4], accZ[2][4], accXN[2][4], accHN[2][4];
#pragma unroll
    for (int rf = 0; rf < 2; ++rf)
#pragma unroll
        for (int q = 0; q < 4; ++q) {
            accR[rf][q] = (f32x4)0.f; accZ[rf][q] = (f32x4)0.f;
            accXN[rf][q] = (f32x4)0.f; accHN[rf][q] = (f32x4)0.f;
        }

    // stage phase pp's 24KB half-slice into bsm[pp&1] via async global_load_lds.
    // wave w copies 3 x 1KB chunks: lds base wave-uniform, global addr per-lane.
    auto stage = [&](int pp) {
        const int k2 = pp >> 1, half2 = pp & 1;
        const ushort_t* base = (k2 >> 2) ? (half2 ? BhLo : BhHi) : (half2 ? BmLo : BmHi);
        const uint4* g = (const uint4*)(base + (size_t)(k2 & 3) * 12288);
        uint4* d = (uint4*)bsm[pp & 1];
        const int cb = wid << 6;   // wave chunk base, uint4 units
#pragma unroll
        for (int i = 0; i < 3; ++i)
            gload_lds16(&g[cb + i * 512 + lane], &d[cb + i * 512]);
    };

    // prologue: A for group 0 + stage phase 0
    uint8v u0 = *(const uint8v*)&aggp[(size_t)ar0 * HD + kcol];
    uint8v u1 = *(const uint8v*)&aggp[(size_t)ar1 * HD + kcol];
    stage(0);
    __syncthreads();

#pragma unroll
    for (int k = 0; k < 8; ++k) {
        const int src = k >> 2;       // 0: agg/Wmi, 1: h/Whh
        // extract A fragments once per group (live across hi+lo)
        short8v a0h, a0l, a1h, a1l;
#pragma unroll
        for (int j = 0; j < 8; ++j) {
            a0h[j] = (short)(u0[j] >> 16); a0l[j] = (short)(u0[j] & 0xffffu);
            a1h[j] = (short)(u1[j] >> 16); a1l[j] = (short)(u1[j] & 0xffffu);
        }
        // ---- hi phase (reads bsm[0]): 2 terms Ah*Bh + Al*Bh ----
        stage(2 * k + 1);
        {
            const ushort_t* bb = bsm[0];
#pragma unroll
            for (int grp = 0; grp < 3; ++grp) {
                auto& gate = (grp == 0) ? accR : (grp == 1) ? accZ : (src == 0) ? accXN : accHN;
#pragma unroll
                for (int q = 0; q < 4; ++q) {
                    int tt = grp * 8 + wc * 4 + q;
                    short8v b = *(const short8v*)&bb[(tt * 64 + lane) * 8];
                    gate[0][q] = mfma16(a0h, b, gate[0][q]);
                    gate[0][q] = mfma16(a0l, b, gate[0][q]);
                    gate[1][q] = mfma16(a1h, b, gate[1][q]);
                    gate[1][q] = mfma16(a1l, b, gate[1][q]);
                }
            }
        }
        __syncthreads();
        // ---- lo phase (reads bsm[1]): 1 term Ah*Bl ----
        if (k < 7) {
            const uint_t* Ap2 = ((k + 1) >> 2) ? hp : aggp;
            const int kb2 = ((k + 1) & 3) * 32 + kcol;
            u0 = *(const uint8v*)&Ap2[(size_t)ar0 * HD + kb2];
            u1 = *(const uint8v*)&Ap2[(size_t)ar1 * HD + kb2];
            stage(2 * k + 2);
        }
        {
            const ushort_t* bb = bsm[1];
#pragma unroll
            for (int grp = 0; grp < 3; ++grp) {
                auto& gate = (grp == 0) ? accR : (grp == 1) ? accZ : (src == 0) ? accXN : accHN;
#pragma unroll
                for (int q = 0; q < 4; ++q) {
                    int tt = grp * 8 + wc * 4 + q;
                    short8v b = *(const short8v*)&bb[(tt * 64 + lane) * 8];
                    gate[0][q] = mfma16(a0h, b, gate[0][q]);
                    gate[1][q] = mfma16(a1h, b, gate[1][q]);
                }
            }
        }
        __syncthreads();
    }

#pragma unroll
    for (int rf = 0; rf < 2; ++rf) {
#pragma unroll
        for (int q = 0; q < 4; ++q) {
            int c = wc * 64 + q * 16 + (lane & 15);
            float bir = bih[c],       bhr = bhh[c];
            float biz = bih[c + 128], bhz = bhh[c + 128];
            float bin_ = bih[c + 256], bhn = bhh[c + 256];
#pragma unroll
            for (int j = 0; j < 4; ++j) {
                int row = row_base + rf * 16 + ((lane >> 4) << 2) + j;
                if (row < N_NODES) {
                    float rr = sigmoid_(accR[rf][q][j] + bir + bhr);
                    float zz = sigmoid_(accZ[rf][q][j] + biz + bhz);
                    float nn = tanhf(accXN[rf][q][j] + bin_ + rr * (accHN[rf][q][j] + bhn));
                    size_t idx = (size_t)row * HD + c;
                    float hold = unpackf(hp[idx]);
                    hp[idx] = packf((1.f - zz) * nn + zz * hold);
                }
            }
        }
    }
}

// ---------------- pooling ----------------
#define POOL_CHUNK 64
__global__ __launch_bounds__(128) void k_pool(const uint_t* __restrict__ hp,
                                              const int* __restrict__ batch,
                                              float* __restrict__ pooled) {
    int t = threadIdx.x;  // 128 cols
    int n0 = blockIdx.x * POOL_CHUNK;
    int nend = n0 + POOL_CHUNK;
    if (nend > N_NODES) nend = N_NODES;
    float acc = 0.f;
    int cur = batch[n0];
    for (int n = n0; n < nend; ++n) {
        int g = batch[n];
        if (g != cur) {
            atomicAdd(&pooled[(size_t)cur * HD + t], acc);
            acc = 0.f;
            cur = g;
        }
        acc += fmaxf(unpackf(hp[(size_t)n * HD + t]), 0.f);  // fused final relu
    }
    atomicAdd(&pooled[(size_t)cur * HD + t], acc);
}

// ---------------- output MLP (counts via binary search on sorted batch) ----------------
__global__ __launch_bounds__(128) void k_out(const float* __restrict__ pooled,
                                             const int* __restrict__ batch,
                                             const float* __restrict__ W1,
                                             const float* __restrict__ b1,
                                             const float* __restrict__ W2,
                                             const float* __restrict__ b2,
                                             float* __restrict__ out) {
    __shared__ float row[128];
    __shared__ float red[128];
    int t = threadIdx.x;
    int g = blockIdx.x;
    int lo0 = 0, hi0 = N_NODES;
    while (lo0 < hi0) { int mid = (lo0 + hi0) >> 1; if (batch[mid] < g) lo0 = mid + 1; else hi0 = mid; }
    int lo1 = lo0, hi1 = N_NODES;
    while (lo1 < hi1) { int mid = (lo1 + hi1) >> 1; if (batch[mid] < g + 1) lo1 = mid + 1; else hi1 = mid; }
    float cnt = (float)(lo1 - lo0);
    if (cnt < 1.f) cnt = 1.f;
    row[t] = pooled[(size_t)g * HD + t] / cnt;
    __syncthreads();
    float acc = b1[t];
#pragma unroll 4
    for (int k = 0; k < HD; ++k) acc += row[k] * W1[k * HD + t];
    float hv = fmaxf(acc, 0.f);
    red[t] = hv * W2[t];
    __syncthreads();
    for (int off = 64; off > 0; off >>= 1) {
        if (t < off) red[t] += red[t + off];
        __syncthreads();
    }
    if (t == 0) {
        float xv = red[0] + b2[0];
        out[g] = fmaxf(xv, 0.f) + log1pf(expf(-fabsf(xv)));
    }
}

extern "C" void kernel_launch(void* const* d_in, const int* in_sizes, int n_in,
                              void* d_out, int out_size, void* d_ws, size_t ws_size,
                              hipStream_t stream) {
    (void)in_sizes; (void)n_in; (void)out_size; (void)ws_size;
    const float* x    = (const float*)d_in[0];
    const int*   ei   = (const int*)d_in[1];
    const int*   batch= (const int*)d_in[2];
    const float* Wemb = (const float*)d_in[3];
    const float* Wmsg = (const float*)d_in[4];
    const float* Wih  = (const float*)d_in[5];
    const float* Whh  = (const float*)d_in[6];
    const float* bih  = (const float*)d_in[7];
    const float* bhh  = (const float*)d_in[8];
    const float* W1   = (const float*)d_in[9];
    const float* b1   = (const float*)d_in[10];
    const float* W2   = (const float*)d_in[11];
    const float* b2   = (const float*)d_in[12];
    float* out = (float*)d_out;

    const int* e_src = ei;
    const int* e_dst = ei + N_EDGES;

    char* ws = (char*)d_ws;
    size_t off = 0;
    auto alloc = [&](size_t bytes) -> void* {
        void* p = ws + off;
        off = (off + bytes + 255) & ~(size_t)255;
        return p;
    };
    uint_t* hp       = (uint_t*)alloc((size_t)N_NODES * HD * 4);
    uint_t* aggp     = (uint_t*)alloc((size_t)N_NODES * HD * 4);
    float* Wmi       = (float*)alloc((size_t)STEPS * 128 * 384 * 4);
    ushort_t* BmHi   = (ushort_t*)alloc((size_t)STEPS * 128 * 384 * 2);
    ushort_t* BmLo   = (ushort_t*)alloc((size_t)STEPS * 128 * 384 * 2);
    ushort_t* BhHi   = (ushort_t*)alloc((size_t)128 * 384 * 2);
    ushort_t* BhLo   = (ushort_t*)alloc((size_t)128 * 384 * 2);
    float* pooled    = (float*)alloc((size_t)N_GRAPHS * HD * 4);
    int* deg         = (int*)alloc((size_t)N_NODES * 4);
    int* row_start   = (int*)alloc((size_t)(N_NODES + 1) * 4);
    int* cursor      = (int*)alloc((size_t)N_NODES * 4);
    int* esrc        = (int*)alloc((size_t)N_EDGES * 4);
    int* bsum        = (int*)alloc((size_t)SCAN_BLOCKS * 4);
    int* bpre        = (int*)alloc((size_t)SCAN_BLOCKS * 4);

    hipMemsetAsync(deg, 0, (size_t)N_NODES * 4, stream);
    hipMemsetAsync(pooled, 0, (size_t)N_GRAPHS * HD * 4, stream);

    k_count<<<(N_EDGES + 255) / 256, 256, 0, stream>>>(e_dst, deg);
    k_bsum<<<SCAN_BLOCKS, 256, 0, stream>>>(deg, bsum);
    k_bscan<<<1, 256, 0, stream>>>(bsum, bpre);
    k_wscan<<<SCAN_BLOCKS, 256, 0, stream>>>(deg, bpre, row_start, cursor);
    k_fill<<<(N_EDGES + 255) / 256, 256, 0, stream>>>(e_src, e_dst, cursor, esrc);

    k_wmi<<<STEPS * 128 * 3, 128, 0, stream>>>(Wmsg, Wih, Wmi);
    k_packB<<<dim3(24, 5), 256, 0, stream>>>(Wmi, Whh, BmHi, BmLo, BhHi, BhLo);

    k_embed<<<512, 256, 0, stream>>>(x, Wemb, hp);

    for (int i = 0; i < STEPS; ++i) {
        k_gather<<<N_NODES / 4, 256, 0, stream>>>(hp, row_start, esrc, aggp);
        k_gru_mfma<<<(N_NODES + GRU_ROWS - 1) / GRU_ROWS, 512, 0, stream>>>(
            aggp, hp,
            BmHi + (size_t)i * 49152, BmLo + (size_t)i * 49152,
            BhHi, BhLo, bih, bhh);
    }

    k_pool<<<(N_NODES + POOL_CHUNK - 1) / POOL_CHUNK, 128, 0, stream>>>(hp, batch, pooled);
    k_out<<<N_GRAPHS, 128, 0, stream>>>(pooled, batch, W1, b1, W2, b2, out);
}